// Round 1
// baseline (10178.529 us; speedup 1.0000x reference)
//
#include <hip/hip_runtime.h>

#define NBLK 8
#define BROWS 131072
#define HDIM 512
#define DHALF 32
#define EPSV 1e-5f

typedef __bf16 bf16x8 __attribute__((ext_vector_type(8)));
typedef float f32x4 __attribute__((ext_vector_type(4)));

__device__ __forceinline__ int swz(int row, int k) {
  return row * HDIM + (k ^ ((row & 7) << 3));
}

__device__ __forceinline__ float act_tanh_f(float x) {
  float e = __expf(2.f * fminf(x, 15.f));
  return (e - 1.f) / (e + 1.f);
}

template <int ACT>
__device__ __forceinline__ float apply_act(float v) {
  if (ACT == 1) return act_tanh_f(v);
  return fmaxf(v, 0.f);
}

// ---------------- MLP layers (M=64 rows/wg, 4 waves x 128-col N-slices) -----

// hidden layer: h (LDS, 64x512 bf16, swizzled) -> h in-place. K=512.
template <int ACT>
__device__ __forceinline__ void dense_h(const __bf16* __restrict__ Wt,
                                        const float* __restrict__ bias,
                                        __bf16* hb, int wave, int c, int quad) {
  const int nb = wave * 128;
  f32x4 acc[4][8];
#pragma unroll
  for (int mt = 0; mt < 4; ++mt)
#pragma unroll
    for (int nt = 0; nt < 8; ++nt) acc[mt][nt] = (f32x4){0.f, 0.f, 0.f, 0.f};

  const int msk = (c & 7) << 3;
  for (int kt = 0; kt < HDIM; kt += 32) {
    const int kq = kt + quad * 8;
    bf16x8 a[4], b[8];
#pragma unroll
    for (int mt = 0; mt < 4; ++mt)
      a[mt] = *(const bf16x8*)&hb[(mt * 16 + c) * HDIM + (kq ^ msk)];
#pragma unroll
    for (int nt = 0; nt < 8; ++nt)
      b[nt] = *(const bf16x8*)&Wt[(size_t)(nb + nt * 16 + c) * HDIM + kq];
#pragma unroll
    for (int mt = 0; mt < 4; ++mt)
#pragma unroll
      for (int nt = 0; nt < 8; ++nt)
        acc[mt][nt] = __builtin_amdgcn_mfma_f32_16x16x32_bf16(a[mt], b[nt], acc[mt][nt], 0, 0, 0);
  }
  __syncthreads();  // all reads of hb done -> safe to overwrite in place
#pragma unroll
  for (int nt = 0; nt < 8; ++nt) {
    const float bs = bias[nb + nt * 16 + c];
#pragma unroll
    for (int mt = 0; mt < 4; ++mt)
#pragma unroll
      for (int i = 0; i < 4; ++i) {
        const int row = mt * 16 + quad * 4 + i;
        float v = apply_act<ACT>(acc[mt][nt][i] + bs);
        hb[swz(row, nb + nt * 16 + c)] = (__bf16)v;
      }
  }
  __syncthreads();
}

// layer 0: ys (registers, A-frags) -> h. K=32.
template <int ACT>
__device__ __forceinline__ void dense_l0(const __bf16* __restrict__ Wt0,
                                         const float* __restrict__ bias,
                                         const bf16x8 aYs[4], __bf16* hb,
                                         int wave, int c, int quad) {
  const int nb = wave * 128;
  f32x4 acc[4][8];
#pragma unroll
  for (int mt = 0; mt < 4; ++mt)
#pragma unroll
    for (int nt = 0; nt < 8; ++nt) acc[mt][nt] = (f32x4){0.f, 0.f, 0.f, 0.f};
  bf16x8 b[8];
#pragma unroll
  for (int nt = 0; nt < 8; ++nt)
    b[nt] = *(const bf16x8*)&Wt0[(size_t)(nb + nt * 16 + c) * 32 + quad * 8];
#pragma unroll
  for (int mt = 0; mt < 4; ++mt)
#pragma unroll
    for (int nt = 0; nt < 8; ++nt)
      acc[mt][nt] = __builtin_amdgcn_mfma_f32_16x16x32_bf16(aYs[mt], b[nt], acc[mt][nt], 0, 0, 0);
  __syncthreads();  // prior readers of hb (head32) done before overwrite
#pragma unroll
  for (int nt = 0; nt < 8; ++nt) {
    const float bs = bias[nb + nt * 16 + c];
#pragma unroll
    for (int mt = 0; mt < 4; ++mt)
#pragma unroll
      for (int i = 0; i < 4; ++i) {
        const int row = mt * 16 + quad * 4 + i;
        float v = apply_act<ACT>(acc[mt][nt][i] + bs);
        hb[swz(row, nb + nt * 16 + c)] = (__bf16)v;
      }
  }
  __syncthreads();
}

// output head: h -> out[2] (N=32, no act). Wave w handles rows w*16..w*16+15.
__device__ __forceinline__ void head32(const __bf16* __restrict__ Wot,
                                       const float* __restrict__ bias,
                                       const __bf16* hb, int wave, int c,
                                       int quad, f32x4 out[2]) {
  f32x4 acc[2] = {(f32x4){0.f, 0.f, 0.f, 0.f}, (f32x4){0.f, 0.f, 0.f, 0.f}};
  const int msk = (c & 7) << 3;
  for (int kt = 0; kt < HDIM; kt += 32) {
    const int kq = kt + quad * 8;
    bf16x8 a = *(const bf16x8*)&hb[(wave * 16 + c) * HDIM + (kq ^ msk)];
#pragma unroll
    for (int nt = 0; nt < 2; ++nt) {
      bf16x8 b = *(const bf16x8*)&Wot[(size_t)(nt * 16 + c) * HDIM + kq];
      acc[nt] = __builtin_amdgcn_mfma_f32_16x16x32_bf16(a, b, acc[nt], 0, 0, 0);
    }
  }
#pragma unroll
  for (int nt = 0; nt < 2; ++nt) {
    const float bs = bias[nt * 16 + c];
#pragma unroll
    for (int i = 0; i < 4; ++i) out[nt][i] = acc[nt][i] + bs;
  }
}

// ---------------- coupling-block kernel -------------------------------------

template <bool FIRST>
__global__ __launch_bounds__(256, 2) void couple_kernel(
    const float* __restrict__ src, float* __restrict__ zbuf,
    float* __restrict__ ld,
    const __bf16* __restrict__ sW0t, const float* __restrict__ sb0,
    const __bf16* __restrict__ sWht, const float* __restrict__ sbh,
    const __bf16* __restrict__ sWot, const float* __restrict__ sbo,
    const __bf16* __restrict__ tW0t, const float* __restrict__ tb0,
    const __bf16* __restrict__ tWht, const float* __restrict__ tbh,
    const __bf16* __restrict__ tWot, const float* __restrict__ tbo,
    const float* __restrict__ prevP,  // A[64], C[64] of previous batchnorm
    float* __restrict__ stats_out,    // sum[64], sumsq[64] accumulators
    int o)                            // ys column offset (0 or 32)
{
  __shared__ __bf16 hbuf[64 * HDIM];  // exactly 64 KiB

  const int tid = threadIdx.x;
  const int wave = tid >> 6;
  const int lane = tid & 63;
  const int c = lane & 15;
  const int quad = lane >> 4;
  const size_t row0 = (size_t)blockIdx.x * 64;

  // ---- phase A: load ys for this tile into A-fragment registers (bf16) ----
  float pA[8], pC[8];
  {
    const int cb = o + quad * 8;
#pragma unroll
    for (int j = 0; j < 8; ++j) {
      pA[j] = FIRST ? 1.f : prevP[cb + j];
      pC[j] = FIRST ? 0.f : prevP[64 + cb + j];
    }
  }
  bf16x8 aYs[4];
#pragma unroll
  for (int mt = 0; mt < 4; ++mt) {
    const size_t r = row0 + mt * 16 + c;
    const float* p = &src[r * 64 + o + quad * 8];
    float4 v0 = *(const float4*)p;
    float4 v1 = *(const float4*)(p + 4);
    float f[8] = {v0.x, v0.y, v0.z, v0.w, v1.x, v1.y, v1.z, v1.w};
#pragma unroll
    for (int j = 0; j < 8; ++j) aYs[mt][j] = (__bf16)(pA[j] * f[j] + pC[j]);
  }

  f32x4 sfr[2], tfr[2];

  // ---- s-net (tanh) ----
  dense_l0<1>(sW0t, sb0, aYs, hbuf, wave, c, quad);
  for (int l = 0; l < 3; ++l)
    dense_h<1>(sWht + (size_t)l * HDIM * HDIM, sbh + l * HDIM, hbuf, wave, c, quad);
  head32(sWot, sbo, hbuf, wave, c, quad, sfr);

  // ---- t-net (relu) ----
  dense_l0<2>(tW0t, tb0, aYs, hbuf, wave, c, quad);
  for (int l = 0; l < 3; ++l)
    dense_h<2>(tWht + (size_t)l * HDIM * HDIM, tbh + l * HDIM, hbuf, wave, c, quad);
  head32(tWot, tbo, hbuf, wave, c, quad, tfr);

  // ---- combine: zc = yc*exp(s)+t ; z ys-half = normalized ys (fp32) -------
  __syncthreads();  // hbuf reads done; reuse as column-stat scratch
  float* colsum = (float*)hbuf;
  float* colsq = colsum + 64;
  if (tid < 128) colsum[tid] = 0.f;
  __syncthreads();

  const int oc = o ^ 32;
  const int rw = (int)row0 + wave * 16;
  float lsum4[4] = {0.f, 0.f, 0.f, 0.f};

#pragma unroll
  for (int nt = 0; nt < 2; ++nt) {  // zc half
    const int col = oc + nt * 16 + c;
    const float A_ = FIRST ? 1.f : prevP[col];
    const float C_ = FIRST ? 0.f : prevP[64 + col];
    float csum = 0.f, csq = 0.f;
#pragma unroll
    for (int i = 0; i < 4; ++i) {
      const int r = rw + quad * 4 + i;
      const size_t idx = (size_t)r * 64 + col;
      float yc = A_ * src[idx] + C_;
      const float s = sfr[nt][i];
      const float zc = yc * __expf(s) + tfr[nt][i];
      zbuf[idx] = zc;
      csum += zc; csq += zc * zc;
      lsum4[i] += s;
    }
    csum += __shfl_xor(csum, 16); csum += __shfl_xor(csum, 32);
    csq  += __shfl_xor(csq, 16);  csq  += __shfl_xor(csq, 32);
    if (quad == 0) { atomicAdd(&colsum[col], csum); atomicAdd(&colsq[col], csq); }
  }
#pragma unroll
  for (int nt = 0; nt < 2; ++nt) {  // ys half (fp32 normalized pass-through)
    const int col = o + nt * 16 + c;
    const float A_ = FIRST ? 1.f : prevP[col];
    const float C_ = FIRST ? 0.f : prevP[64 + col];
    float csum = 0.f, csq = 0.f;
#pragma unroll
    for (int i = 0; i < 4; ++i) {
      const int r = rw + quad * 4 + i;
      const size_t idx = (size_t)r * 64 + col;
      float v = A_ * src[idx] + C_;
      zbuf[idx] = v;
      csum += v; csq += v * v;
    }
    csum += __shfl_xor(csum, 16); csum += __shfl_xor(csum, 32);
    csq  += __shfl_xor(csq, 16);  csq  += __shfl_xor(csq, 32);
    if (quad == 0) { atomicAdd(&colsum[col], csum); atomicAdd(&colsq[col], csq); }
  }

  // per-row logdet contribution: sum_j s_out[j]
#pragma unroll
  for (int i = 0; i < 4; ++i) {
    float v = lsum4[i];
    v += __shfl_xor(v, 1); v += __shfl_xor(v, 2);
    v += __shfl_xor(v, 4); v += __shfl_xor(v, 8);
    if (c == 0) {
      const int r = rw + quad * 4 + i;
      if (FIRST) ld[r] = v; else ld[r] += v;
    }
  }

  __syncthreads();
  if (tid < 64) {
    atomicAdd(&stats_out[tid], colsum[tid]);
    atomicAdd(&stats_out[64 + tid], colsq[tid]);
  }
}

// ---------------- small kernels ---------------------------------------------

__global__ void stats_kernel(const float* __restrict__ raw,
                             const float* __restrict__ lg,
                             const float* __restrict__ beta,
                             float* __restrict__ param,
                             float* __restrict__ ld_scalar) {
  const int t = threadIdx.x;  // 64 threads
  const float S = raw[t], SS = raw[64 + t];
  const float mean = S / (float)BROWS;
  const float var = (SS - S * mean) / (float)(BROWS - 1);
  const float inv = rsqrtf(var + EPSV);
  const float g = __expf(lg[t]);
  const float A = g * inv;
  param[t] = A;
  param[64 + t] = beta[t] - mean * A;
  float contrib = lg[t] - 0.5f * __logf(var + EPSV);
  contrib += __shfl_xor(contrib, 1);  contrib += __shfl_xor(contrib, 2);
  contrib += __shfl_xor(contrib, 4);  contrib += __shfl_xor(contrib, 8);
  contrib += __shfl_xor(contrib, 16); contrib += __shfl_xor(contrib, 32);
  if (t == 0) atomicAdd(ld_scalar, contrib);
}

__global__ void final_kernel(float* __restrict__ out,
                             const float* __restrict__ param7,
                             const float* __restrict__ ld_scalar) {
  const size_t gid = (size_t)blockIdx.x * 256 + threadIdx.x;
  const size_t total = (size_t)BROWS * 64;
  const int col = gid & 63;
  const float z = out[gid];
  out[gid] = param7[col] * z + param7[64 + col];
  if (gid < BROWS) out[total + gid] += ld_scalar[0];
}

// W[k][n] (fp32) -> Wt[n][k] (bf16)
__global__ void transpose_bf16(const float* __restrict__ src,
                               __bf16* __restrict__ dst, int K, int N) {
  __shared__ float tile[32][33];
  const int bz = blockIdx.z;
  const float* s = src + (size_t)bz * K * N;
  __bf16* dd = dst + (size_t)bz * K * N;
  const int tx = threadIdx.x, ty = threadIdx.y;  // 32 x 8
#pragma unroll
  for (int i = 0; i < 4; ++i) {
    const int k = blockIdx.y * 32 + ty + i * 8;
    const int n = blockIdx.x * 32 + tx;
    tile[ty + i * 8][tx] = s[(size_t)k * N + n];
  }
  __syncthreads();
#pragma unroll
  for (int i = 0; i < 4; ++i) {
    const int n = blockIdx.x * 32 + ty + i * 8;
    const int k = blockIdx.y * 32 + tx;
    dd[(size_t)n * K + k] = (__bf16)tile[tx][ty + i * 8];
  }
}

// ---------------- launcher --------------------------------------------------

extern "C" void kernel_launch(void* const* d_in, const int* in_sizes, int n_in,
                              void* d_out, int out_size, void* d_ws, size_t ws_size,
                              hipStream_t stream) {
  const float* y_in = (const float*)d_in[0];
  const float* sW0 = (const float*)d_in[1];
  const float* sb0 = (const float*)d_in[2];
  const float* sWh = (const float*)d_in[3];
  const float* sbh = (const float*)d_in[4];
  const float* sWo = (const float*)d_in[5];
  const float* sbo = (const float*)d_in[6];
  const float* tW0 = (const float*)d_in[7];
  const float* tb0 = (const float*)d_in[8];
  const float* tWh = (const float*)d_in[9];
  const float* tbh = (const float*)d_in[10];
  const float* tWo = (const float*)d_in[11];
  const float* tbo = (const float*)d_in[12];
  const float* bn_lg = (const float*)d_in[13];
  const float* bn_bt = (const float*)d_in[14];

  char* p = (char*)d_ws;
  __bf16* sW0t = (__bf16*)p; p += (size_t)NBLK * 32 * 512 * 2;
  __bf16* sWht = (__bf16*)p; p += (size_t)NBLK * 3 * 512 * 512 * 2;
  __bf16* sWot = (__bf16*)p; p += (size_t)NBLK * 512 * 32 * 2;
  __bf16* tW0t = (__bf16*)p; p += (size_t)NBLK * 32 * 512 * 2;
  __bf16* tWht = (__bf16*)p; p += (size_t)NBLK * 3 * 512 * 512 * 2;
  __bf16* tWot = (__bf16*)p; p += (size_t)NBLK * 512 * 32 * 2;
  float* stats_raw = (float*)p; p += NBLK * 128 * 4;
  float* ld_scalar = (float*)p; p += 16;
  float* stats_param = (float*)p; p += NBLK * 128 * 4;

  float* out = (float*)d_out;
  float* zbuf = out;                           // z lives in d_out's y region
  float* ld = out + (size_t)BROWS * 64;

  dim3 tb(32, 8, 1);
  transpose_bf16<<<dim3(16, 1, 8),  tb, 0, stream>>>(sW0, sW0t, 32, 512);
  transpose_bf16<<<dim3(16, 16, 24), tb, 0, stream>>>(sWh, sWht, 512, 512);
  transpose_bf16<<<dim3(1, 16, 8),  tb, 0, stream>>>(sWo, sWot, 512, 32);
  transpose_bf16<<<dim3(16, 1, 8),  tb, 0, stream>>>(tW0, tW0t, 32, 512);
  transpose_bf16<<<dim3(16, 16, 24), tb, 0, stream>>>(tWh, tWht, 512, 512);
  transpose_bf16<<<dim3(1, 16, 8),  tb, 0, stream>>>(tWo, tWot, 512, 32);
  hipMemsetAsync(stats_raw, 0, NBLK * 128 * 4 + 16, stream);

  for (int b = 0; b < NBLK; ++b) {
    const int o = (b & 1) ? 32 : 0;
    const __bf16* W0t_ = sW0t + (size_t)b * 16384;
    const __bf16* Wht_ = sWht + (size_t)b * 3 * 512 * 512;
    const __bf16* Wot_ = sWot + (size_t)b * 16384;
    const __bf16* tW0t_ = tW0t + (size_t)b * 16384;
    const __bf16* tWht_ = tWht + (size_t)b * 3 * 512 * 512;
    const __bf16* tWot_ = tWot + (size_t)b * 16384;
    const float* pb0 = sb0 + b * 512;
    const float* pbh = sbh + b * 1536;
    const float* pbo = sbo + b * 32;
    const float* qb0 = tb0 + b * 512;
    const float* qbh = tbh + b * 1536;
    const float* qbo = tbo + b * 32;
    float* praw = stats_raw + b * 128;

    if (b == 0)
      couple_kernel<true><<<BROWS / 64, 256, 0, stream>>>(
          y_in, zbuf, ld, W0t_, pb0, Wht_, pbh, Wot_, pbo,
          tW0t_, qb0, tWht_, qbh, tWot_, qbo, nullptr, praw, o);
    else
      couple_kernel<false><<<BROWS / 64, 256, 0, stream>>>(
          zbuf, zbuf, ld, W0t_, pb0, Wht_, pbh, Wot_, pbo,
          tW0t_, qb0, tWht_, qbh, tWot_, qbo,
          stats_param + (size_t)(b - 1) * 128, praw, o);

    stats_kernel<<<1, 64, 0, stream>>>(praw, bn_lg + b * 64, bn_bt + b * 64,
                                       stats_param + (size_t)b * 128, ld_scalar);
  }

  final_kernel<<<(BROWS * 64) / 256, 256, 0, stream>>>(
      out, stats_param + 7 * 128, ld_scalar);
}